// Round 4
// baseline (766.167 us; speedup 1.0000x reference)
//
#include <hip/hip_runtime.h>
#include <hip/hip_fp16.h>

#define T_DIM 2048
#define B_DIM 16
#define D_DIM 1024
#define M_TOT (T_DIM * B_DIM)   // 32768
#define K_TOT D_DIM             // 1024
#define BD    (B_DIM * D_DIM)   // 16384 chains
#define XN    ((size_t)M_TOT * K_TOT)        // 33554432 x elems
#define WN    ((size_t)D_DIM * K_TOT)        // 1048576 per W

typedef __attribute__((ext_vector_type(8))) short short8;
typedef __attribute__((ext_vector_type(4))) float floatx4;

__device__ __forceinline__ short f32_to_bf16(float f) {
  unsigned u = __float_as_uint(f);
  u = (u + 0x7FFFu + ((u >> 16) & 1u)) >> 16;   // RNE
  return (short)u;
}

// ---------------- single cast kernel: [x | W_alpha | W_x] -> bf16 ----------------
// dst region is contiguous (xb then wb) so dst = xb + i for all three sources.
__global__ __launch_bounds__(256) void cast_all_k(const float* __restrict__ x,
                                                  const float* __restrict__ Wa,
                                                  const float* __restrict__ Wx,
                                                  short* __restrict__ xb) {
  const size_t i = ((size_t)blockIdx.x * 256 + threadIdx.x) * 8;
  const float* src; size_t si;            // block-uniform branch
  if (i < XN)           { src = x;  si = i; }
  else if (i < XN + WN) { src = Wa; si = i - XN; }
  else                  { src = Wx; si = i - XN - WN; }
  floatx4 f0 = *(const floatx4*)(src + si);
  floatx4 f1 = *(const floatx4*)(src + si + 4);
  short8 o;
  o[0] = f32_to_bf16(f0[0]); o[1] = f32_to_bf16(f0[1]);
  o[2] = f32_to_bf16(f0[2]); o[3] = f32_to_bf16(f0[3]);
  o[4] = f32_to_bf16(f1[0]); o[5] = f32_to_bf16(f1[1]);
  o[6] = f32_to_bf16(f1[2]); o[7] = f32_to_bf16(f1[3]);
  *(short8*)(xb + i) = o;
}

// ---------------- fused dual-GEMM + activation epilogue ----------------
// C-tile 128m x 128c; c-groups of 16 alternate planes: g=0..7 -> plane=g&1
// (0:W_alpha,1:W_x), e_off=(g>>1)*16. Block covers e in [eblk, eblk+64).
// A staged via global_load_lds (LDS traffic halved vs staging both); B-frags
// loaded straight global->VGPR (W is 4MB -> L2-resident; 16B/lane dense).
// Epilogue: each thread holds alpha (acc[i][2p]) and v (acc[i][2p+1]) for the
// SAME e -> one dense __half2 store, no read-modify-write.
#define GLDS16(gp, lp)                                                                   \
  __builtin_amdgcn_global_load_lds((const __attribute__((address_space(1))) void*)(gp),  \
                                   (__attribute__((address_space(3))) void*)(lp), 16, 0, 0)

__global__ __launch_bounds__(256, 2) void gemm_act_k(
    const short* __restrict__ xb, const short* __restrict__ wb,
    const float* __restrict__ b_alpha, const float* __restrict__ b_v,
    __half2* __restrict__ pairbuf) {
  __shared__ __align__(16) short As[128 * 32];
  const int tid  = threadIdx.x;
  const int wave = tid >> 6;
  const int lane = tid & 63;
  const int quad = lane >> 4;
  const int l16  = lane & 15;
  const int mblk = blockIdx.y << 7;
  const int eblk = blockIdx.x << 6;
  const int wrow = (wave >> 1) << 6;
  const int wcol = (wave & 1) << 6;

  floatx4 acc[4][4];
#pragma unroll
  for (int i = 0; i < 4; ++i)
#pragma unroll
    for (int j = 0; j < 4; ++j) acc[i][j] = {0.f, 0.f, 0.f, 0.f};

  // A staging: thread stages 16B of row chunk_m (and +64), k-chunk tid&3
  const int chunk_m = tid >> 2;
  const short* gA0 = xb + (size_t)(mblk + chunk_m) * K_TOT + (tid & 3) * 8;
  const short* gA1 = gA0 + (size_t)64 * K_TOT;
  short* lA0 = As + wave * 512;          // wave-uniform base; HW appends lane*16B
  short* lA1 = As + 2048 + wave * 512;
  const int aoff = (wrow + l16) * 32 + quad * 8;

  // B-frag global pointers (per-thread constant; add k0 in loop)
  const short* gB[4];
#pragma unroll
  for (int j = 0; j < 4; ++j) {
    const int g = (wcol >> 4) + j;
    const int row = (g & 1) * D_DIM + eblk + ((g >> 1) << 4) + l16;
    gB[j] = wb + (size_t)row * K_TOT + quad * 8;
  }

  for (int k0 = 0; k0 < K_TOT; k0 += 32) {
    short8 bf[4];
#pragma unroll
    for (int j = 0; j < 4; ++j) bf[j] = *(const short8*)(gB[j] + k0);
    GLDS16(gA0 + k0, lA0);
    GLDS16(gA1 + k0, lA1);
    __syncthreads();
    short8 af[4];
#pragma unroll
    for (int i = 0; i < 4; ++i) af[i] = *(const short8*)(As + aoff + i * 512);
#pragma unroll
    for (int i = 0; i < 4; ++i)
#pragma unroll
      for (int j = 0; j < 4; ++j)
        acc[i][j] = __builtin_amdgcn_mfma_f32_16x16x32_bf16(af[i], bf[j], acc[i][j], 0, 0, 0);
    __syncthreads();
  }

#pragma unroll
  for (int p = 0; p < 2; ++p) {
    const int e = eblk + (wcol >> 1) + p * 16 + l16;
    const float ba = b_alpha[e];
    const float bv = b_v[e];
#pragma unroll
    for (int i = 0; i < 4; ++i) {
      const floatx4 va = acc[i][2 * p];
      const floatx4 vv = acc[i][2 * p + 1];
      const int m_base = mblk + wrow + i * 16 + quad * 4;  // D: row = quad*4+reg, col = l16
#pragma unroll
      for (int r = 0; r < 4; ++r) {
        const float za = va[r] + ba;
        const float zv = vv[r] + bv;
        const float alpha = __builtin_amdgcn_rcpf(1.f + __expf(-za));                 // sigmoid
        const float vtanh = 1.f - 2.f * __builtin_amdgcn_rcpf(__expf(2.f * zv) + 1.f); // tanh
        pairbuf[(size_t)(m_base + r) * D_DIM + e] =
            __halves2half2(__float2half(alpha), __float2half(vtanh));
      }
    }
  }
}

// ---------------- sequential scan: h-recurrence only, fp16 h out ----------------
// 32-deep register ring prefetch (HBM latency ~900cyc needs ~30 outstanding).
__global__ __launch_bounds__(64) void scan_k(const __half2* __restrict__ pair,
                                             const float* __restrict__ d_g,
                                             const float* __restrict__ b_g,
                                             __half* __restrict__ hh) {
  const int c = blockIdx.x * 64 + threadIdx.x;   // chain id = b*D + d
  const float LOG2E = 1.44269504f;
  const float dg = d_g[c & (D_DIM - 1)] * LOG2E;
  const float bg = b_g[c & (D_DIM - 1)] * LOG2E;
  hh[c] = __float2half(0.f);                     // h0
  float h = 0.f;
  size_t idx = c;
  __half2 p[32];
#pragma unroll
  for (int k = 0; k < 32; ++k) p[k] = pair[idx + (size_t)k * BD];
  for (int t = 0; t < T_DIM; t += 32) {
    const size_t pfadd = (t + 32 < T_DIM) ? (size_t)32 * BD : 0;
#pragma unroll
    for (int k = 0; k < 32; ++k) {
      const float2 av = __half22float2(p[k]);    // .x = alpha, .y = v_raw
      p[k] = pair[idx + pfadd];                  // prefetch step t+k+32
      const float w = (1.f - av.x) * av.y;       // off critical path
      const float e = __builtin_amdgcn_exp2f(fmaf(dg, fabsf(h), -bg));
      const float g = __builtin_amdgcn_rcpf(1.f + e);
      h = fmaf(av.x, h, w * g);                  // alpha*h + (1-alpha)*v*g
      hh[idx + BD] = __float2half(h);
      idx += BD;
    }
  }
}

// ---------------- parallel epilogue: expand h fp16->fp32, out = h^2 * sigmoid(h) ----
__global__ __launch_bounds__(256) void silu_k(const __half* __restrict__ hh,
                                              float* __restrict__ outbuf) {
  const float LOG2E = 1.44269504f;
  const size_t i = ((size_t)blockIdx.x * 256 + threadIdx.x) * 8;  // i < (T+1)*BD
  float* __restrict__ outs = outbuf;                       // [T, B*D]
  float* __restrict__ hout = outbuf + (size_t)T_DIM * BD;  // [T+1, B*D]
  const __half2* hp = (const __half2*)(hh + i);
  float hf[8];
#pragma unroll
  for (int j = 0; j < 4; ++j) {
    const float2 f = __half22float2(hp[j]);
    hf[2 * j] = f.x; hf[2 * j + 1] = f.y;
  }
  *(floatx4*)(hout + i)     = floatx4{hf[0], hf[1], hf[2], hf[3]};
  *(floatx4*)(hout + i + 4) = floatx4{hf[4], hf[5], hf[6], hf[7]};
  if (i >= BD) {                                           // block-uniform
    float o[8];
#pragma unroll
    for (int j = 0; j < 8; ++j) {
      const float s = __builtin_amdgcn_rcpf(1.f + __builtin_amdgcn_exp2f(-LOG2E * hf[j]));
      o[j] = hf[j] * hf[j] * s;                            // h * silu(h)
    }
    *(floatx4*)(outs + i - BD)     = floatx4{o[0], o[1], o[2], o[3]};
    *(floatx4*)(outs + i - BD + 4) = floatx4{o[4], o[5], o[6], o[7]};
  }
}

extern "C" void kernel_launch(void* const* d_in, const int* in_sizes, int n_in,
                              void* d_out, int out_size, void* d_ws, size_t ws_size,
                              hipStream_t stream) {
  const float* x       = (const float*)d_in[0];
  const float* W_alpha = (const float*)d_in[1];
  const float* b_alpha = (const float*)d_in[2];
  const float* d_g     = (const float*)d_in[3];
  const float* b_g     = (const float*)d_in[4];
  const float* W_x     = (const float*)d_in[5];
  const float* b_v     = (const float*)d_in[6];
  float* out = (float*)d_out;

  // ws layout: xb (64MB) | wb (4MB, contiguous after xb) | pairbuf (128MB).
  // h_half (67.1MB) ALIASES xb+wb (dead after gemm_act_k).
  char* ws = (char*)d_ws;
  short*   xb      = (short*)ws;                                 // [32768][1024] bf16
  short*   wb      = (short*)(ws + (size_t)67108864);            // [2048][1024] bf16
  __half2* pairbuf = (__half2*)(ws + (size_t)71303168);          // [32768][1024] (alpha,v)
  __half*  h_half  = (__half*)ws;                                // [2049][16384] fp16

  cast_all_k<<<(XN + 2 * WN) / (8 * 256), 256, 0, stream>>>(x, W_alpha, W_x, xb);
  gemm_act_k<<<dim3(D_DIM / 64, M_TOT / 128), 256, 0, stream>>>(xb, wb, b_alpha, b_v, pairbuf);
  scan_k<<<BD / 64, 64, 0, stream>>>(pairbuf, d_g, b_g, h_half);
  silu_k<<<(T_DIM + 1) * BD / (8 * 256), 256, 0, stream>>>(h_half, out);
}